// Round 5
// baseline (6409.656 us; speedup 1.0000x reference)
//
#include <hip/hip_runtime.h>
#include <hip/hip_fp16.h>

// SoftRR: n=1024, m=8192, rounds=8, TAU=1.0
//   scan over 8192 rows (V tiled x8):
//     y = softmax((row - min(row) + 1) * c);  c = (1-y)*c
//   pi[i][j] = sum over rounds of y
//
// R5: packed-f32 scan.
//  - R4 proved the scan is VALU-issue bound (~1030 cy issue of 1427 cy/step).
//  - All elementwise math now on float2 vectors -> backend emits
//    v_pk_{mul,add,fma}_f32 (2 f32/instr, gfx90a+): halves issue for
//    z-mul, tree-sum, y-mul, c-update.
//  - A precomputed in f32 (kills 16x v_cvt_f32_f16 per thread per step),
//    stored in d_out (32 MiB, exactly out_size) in a thread-permuted layout
//    so each of the 4 per-thread dwordx4 loads is lane-contiguous.
//  - Scan stays store-only into R[8192][8192] f16 (128 MiB ws); full-chip
//    epilogue sums 8 round-slices -> d_out (overwrites the A scratch).
//  - Reductions on DPP (VALU pipe); barrier is lgkmcnt-only.

#define N_ROWS 1024
#define M_COLS 8192
#define STEPS  8192
#define LOG2E  1.4426950408889634f

using half8  = __attribute__((ext_vector_type(8))) _Float16;
using half2v = __attribute__((ext_vector_type(2))) _Float16;
using f32x2  = __attribute__((ext_vector_type(2))) float;

__device__ __forceinline__ float fast_exp2(float x) {
#if __has_builtin(__builtin_amdgcn_exp2f)
  return __builtin_amdgcn_exp2f(x);
#else
  return exp2f(x);
#endif
}
__device__ __forceinline__ float fast_rcp(float x) {
#if __has_builtin(__builtin_amdgcn_rcpf)
  return __builtin_amdgcn_rcpf(x);
#else
  return 1.0f / x;
#endif
}
__device__ __forceinline__ half2v pack_f16(float y0, float y1) {
  return __builtin_bit_cast(half2v, __builtin_amdgcn_cvt_pkrtz(y0, y1));
}

template <int CTRL>
__device__ __forceinline__ float dpp_add(float x) {
  int yi = __builtin_amdgcn_update_dpp(0, __builtin_bit_cast(int, x),
                                       CTRL, 0xf, 0xf, true);
  return x + __builtin_bit_cast(float, yi);
}

// full 64-lane sum; result valid in lane 63
__device__ __forceinline__ float wave_sum_to_lane63(float x) {
  x = dpp_add<0x111>(x);  // row_shr:1
  x = dpp_add<0x112>(x);  // row_shr:2
  x = dpp_add<0x114>(x);  // row_shr:4
  x = dpp_add<0x118>(x);  // row_shr:8   -> lane15 of each row = row sum
  x = dpp_add<0x142>(x);  // row_bcast15
  x = dpp_add<0x143>(x);  // row_bcast31 -> lane63 = total
  return x;
}

// barrier WITHOUT vmcnt drain: only LDS ops must be visible across it
#define BAR_LDS_ONLY() asm volatile("s_waitcnt lgkmcnt(0)\n\ts_barrier" ::: "memory")

// ---------------- rowmin: one block per row ----------------
__global__ void softrr_rowmin(const float* __restrict__ V, float* __restrict__ rmin) {
  const int row = blockIdx.x;
  const float* p = V + (size_t)row * M_COLS;
  float m = 1e30f;
  for (int j = threadIdx.x; j < M_COLS; j += 256) m = fminf(m, p[j]);
#pragma unroll
  for (int off = 32; off; off >>= 1) m = fminf(m, __shfl_xor(m, off, 64));
  __shared__ float sm[4];
  if ((threadIdx.x & 63) == 0) sm[threadIdx.x >> 6] = m;
  __syncthreads();
  if (threadIdx.x == 0) {
    rmin[row] = fminf(fminf(sm[0], sm[1]), fminf(sm[2], sm[3]));
  }
}

// ---------------- prep: A' = (V - rowmin + 1)*log2e, f32, permuted ----------------
// Layout: A'[row*8192 + q*2048 + 4*t + e] = a[row][16*t + 4*q + e],
// q in [0,4), t in [0,512), e in [0,4).  So scan load q of thread t is
// lane-contiguous (16 B per lane).
__global__ void softrr_prep_f32(const float* __restrict__ V, const float* __restrict__ rmin,
                                float* __restrict__ A) {
  const int gid = blockIdx.x * 256 + threadIdx.x;   // 2M float4 outputs
  const int row = gid >> 11;                        // 2048 float4 per row
  const int w   = gid & 2047;
  const int q   = w >> 9;
  const int t   = w & 511;
  const float mn = rmin[row];
  const float4* V4 = (const float4*)V;
  float4 v = V4[row * 2048 + 4 * t + q];            // cols 16t+4q .. +3
  float4 o;
  o.x = (v.x - mn + 1.0f) * LOG2E;
  o.y = (v.y - mn + 1.0f) * LOG2E;
  o.z = (v.z - mn + 1.0f) * LOG2E;
  o.w = (v.w - mn + 1.0f) * LOG2E;
  ((float4*)A)[gid] = o;
}

// ---------------- main scan: 512 thr, 16 cols/thread, packed f32 ----------------
__global__ void __launch_bounds__(512) softrr_scan_pk(const float* __restrict__ Af,
                                                      __half* __restrict__ Rh) {
  const int t = threadIdx.x;          // owns cols 16t..16t+15
  const int wave = t >> 6;            // 0..7
  const int lane = t & 63;
  __shared__ float sP[2][8];

  const float4* __restrict__ A4 = (const float4*)Af;
  half8* __restrict__ R8 = (half8*)Rh;

  f32x2 c[8];
#pragma unroll
  for (int k = 0; k < 8; ++k) c[k] = (f32x2){1.0f, 1.0f};

  // A prefetch ring, 2 rows deep; load q of row i at A4[i*2048 + q*512 + t]
  float4 cur[4], nxt[4];
#pragma unroll
  for (int q = 0; q < 4; ++q) cur[q] = A4[q * 512 + t];
#pragma unroll
  for (int q = 0; q < 4; ++q) nxt[q] = A4[2048 + q * 512 + t];

  for (int s = 0; s < STEPS; ++s) {
    const int ld  = (s + 2) & (N_ROWS - 1);
    const int par = s & 1;

    float4 inc[4];
#pragma unroll
    for (int q = 0; q < 4; ++q) inc[q] = A4[ld * 2048 + q * 512 + t];

    // pairs: a[2q] = {cur[q].x, cur[q].y}, a[2q+1] = {cur[q].z, cur[q].w}
    f32x2 z[8];
#pragma unroll
    for (int q = 0; q < 4; ++q) {
      z[2 * q]     = (f32x2){cur[q].x, cur[q].y} * c[2 * q];
      z[2 * q + 1] = (f32x2){cur[q].z, cur[q].w} * c[2 * q + 1];
    }

    f32x2 e[8];
#pragma unroll
    for (int k = 0; k < 8; ++k) {
      e[k][0] = fast_exp2(z[k][0]);
      e[k][1] = fast_exp2(z[k][1]);
    }

    // pairwise vector tree sum -> scalar
    f32x2 t0 = (e[0] + e[1]) + (e[2] + e[3]);
    f32x2 t1 = (e[4] + e[5]) + (e[6] + e[7]);
    f32x2 tw = t0 + t1;
    float l = tw[0] + tw[1];

    l = wave_sum_to_lane63(l);
    if (lane == 63) sP[par][wave] = l;
    BAR_LDS_ONLY();

    float x = (lane < 8) ? sP[par][lane] : 0.0f;
    x = dpp_add<0x111>(x);
    x = dpp_add<0x112>(x);
    x = dpp_add<0x114>(x);
    const float S = __builtin_bit_cast(
        float, __builtin_amdgcn_readlane(__builtin_bit_cast(int, x), 7));
    const float Sinv = fast_rcp(S);
    const f32x2 Sv = (f32x2){Sinv, Sinv};

    f32x2 y[8];
#pragma unroll
    for (int k = 0; k < 8; ++k) {
      y[k] = e[k] * Sv;          // v_pk_mul_f32
      c[k] = c[k] - y[k] * c[k]; // contracts to v_pk_fma_f32 with neg
    }

    half8 o0, o1;
#pragma unroll
    for (int k = 0; k < 4; ++k) {
      half2v h = pack_f16(y[k][0], y[k][1]);
      o0[2 * k] = h[0]; o0[2 * k + 1] = h[1];
    }
#pragma unroll
    for (int k = 0; k < 4; ++k) {
      half2v h = pack_f16(y[4 + k][0], y[4 + k][1]);
      o1[2 * k] = h[0]; o1[2 * k + 1] = h[1];
    }
    R8[(size_t)s * 1024 + 2 * t]     = o0;
    R8[(size_t)s * 1024 + 2 * t + 1] = o1;

#pragma unroll
    for (int q = 0; q < 4; ++q) { cur[q] = nxt[q]; nxt[q] = inc[q]; }
  }
}

// ---------------- epilogue: out[i][j] = sum_r R[r*1024+i][j] (f32) ----------------
__global__ void softrr_sum8(const __half* __restrict__ Rh, float* __restrict__ out) {
  const int idx8 = blockIdx.x * 256 + threadIdx.x;   // 1M half8 outputs
  const half8* R8 = (const half8*)Rh;
  float acc[8];
  {
    half8 v = R8[idx8];
#pragma unroll
    for (int k = 0; k < 8; ++k) acc[k] = (float)v[k];
  }
#pragma unroll
  for (int r = 1; r < 8; ++r) {
    half8 v = R8[(size_t)r * 1024 * 1024 + idx8];
#pragma unroll
    for (int k = 0; k < 8; ++k) acc[k] += (float)v[k];
  }
  ((float4*)out)[2 * idx8]     = make_float4(acc[0], acc[1], acc[2], acc[3]);
  ((float4*)out)[2 * idx8 + 1] = make_float4(acc[4], acc[5], acc[6], acc[7]);
}

// ---------------- fallback: f32 direct (tiny ws) ----------------
__global__ void __launch_bounds__(1024) softrr_scan_b(const float* __restrict__ V,
                                                      const float* __restrict__ rmin,
                                                      float* __restrict__ out) {
  const int t = threadIdx.x;
  const int wave = t >> 6;
  const int lane = t & 63;
  __shared__ float partials[2][16];
  __shared__ float smin[N_ROWS];
  smin[t] = rmin[t];
  __syncthreads();
  const float4* __restrict__ V4 = (const float4*)V;
  float4* O4 = (float4*)out;
  float c[8];
#pragma unroll
  for (int k = 0; k < 8; ++k) c[k] = 1.0f;
  float4 va = V4[2 * t], vb = V4[2 * t + 1];
  float4 pa, pb;
  for (int s = 0; s < STEPS; ++s) {
    const int i = s & (N_ROWS - 1);
    const int r = s >> 10;
    const int in_ = (s + 1) & (N_ROWS - 1);
    float4 van = V4[in_ * 2048 + 2 * t];
    float4 vbn = V4[in_ * 2048 + 2 * t + 1];
    const float mn = smin[i];
    const float base = (1.0f - mn) * LOG2E;
    float vv[8] = {va.x, va.y, va.z, va.w, vb.x, vb.y, vb.z, vb.w};
    float e[8];
    float l = 0.0f;
#pragma unroll
    for (int k = 0; k < 8; ++k) {
      float zb = __builtin_fmaf(vv[k], LOG2E, base);
      e[k] = fast_exp2(zb * c[k]);
      l += e[k];
    }
#pragma unroll
    for (int off = 32; off; off >>= 1) l += __shfl_xor(l, off, 64);
    if (lane == 0) partials[s & 1][wave] = l;
    __syncthreads();
    float S = 0.0f;
#pragma unroll
    for (int w = 0; w < 16; ++w) S += partials[s & 1][w];
    const float Sinv = fast_rcp(S);
    float po[8] = {pa.x, pa.y, pa.z, pa.w, pb.x, pb.y, pb.z, pb.w};
    float o[8];
#pragma unroll
    for (int k = 0; k < 8; ++k) {
      float y = e[k] * Sinv;
      c[k] = __builtin_fmaf(-y, c[k], c[k]);
      o[k] = (r > 0) ? (po[k] + y) : y;
    }
    O4[i * 2048 + 2 * t]     = make_float4(o[0], o[1], o[2], o[3]);
    O4[i * 2048 + 2 * t + 1] = make_float4(o[4], o[5], o[6], o[7]);
    va = van; vb = vbn;
    pa = O4[in_ * 2048 + 2 * t];
    pb = O4[in_ * 2048 + 2 * t + 1];
  }
}

extern "C" void kernel_launch(void* const* d_in, const int* in_sizes, int n_in,
                              void* d_out, int out_size, void* d_ws, size_t ws_size,
                              hipStream_t stream) {
  const float* V = (const float*)d_in[0];
  float* out = (float*)d_out;
  float* rmin = (float*)d_ws;

  const size_t R_BYTES = (size_t)STEPS * M_COLS * 2;   // 128 MiB
  const size_t need = 4096 + R_BYTES;

  if (ws_size >= need) {
    // A (f32, 32 MiB) lives in d_out; final sum8 overwrites it.
    float* A  = out;
    __half* R = (__half*)((char*)d_ws + 4096);
    softrr_rowmin<<<N_ROWS, 256, 0, stream>>>(V, rmin);
    softrr_prep_f32<<<8192, 256, 0, stream>>>(V, rmin, A);
    softrr_scan_pk<<<1, 512, 0, stream>>>(A, R);
    softrr_sum8<<<4096, 256, 0, stream>>>(R, out);
  } else {
    softrr_rowmin<<<N_ROWS, 256, 0, stream>>>(V, rmin);
    softrr_scan_b<<<1, 1024, 0, stream>>>(V, rmin, out);
  }
}

// Round 6
// 5149.112 us; speedup vs baseline: 1.2448x; 1.2448x over previous
//
#include <hip/hip_runtime.h>
#include <hip/hip_fp16.h>

// SoftRR: n=1024, m=8192, rounds=8, TAU=1.0
//   scan over 8192 rows (V tiled x8):
//     y = softmax((row - min(row) + 1) * c);  c = (1-y)*c
//   pi[i][j] = sum over rounds of y
//
// R6: "shadow store" scan.
//  - R4 proved: store-only scan, fp16 A (2 loads/step) -> 1427 cy/step.
//  - R5 proved: f32 A doubles fetch and regresses; packing alone isn't it.
//  - Now the scan stores UNNORMALIZED e = exp2(a*c) in fp16 plus Sinv[s]
//    (1 scalar/step); epilogue computes pi = sum_r e * Sinv (it's
//    memory-bound, the fma is free). So the e-pack, both R-stores and
//    ce = c*e all issue BEFORE the barrier (in the reduce's shadow); the
//    only S-dependent work left is c -= ce*Sinv (8 v_pk_fma_f32).
//  - z = (float)a_f16 * c_f32 -> v_fma_mix_f32 (no cvt); tree-sum and
//    c-math on f32x2 (v_pk_*); reductions on DPP; barrier lgkmcnt-only.
//  - A (fp16, 16 MiB) lives in d_out's first half (scan reads it, epilogue
//    overwrites d_out afterwards). ws = rmin | E(128 MiB) | Sinv(32 KiB).

#define N_ROWS 1024
#define M_COLS 8192
#define STEPS  8192
#define LOG2E  1.4426950408889634f

using half8  = __attribute__((ext_vector_type(8))) _Float16;
using half2v = __attribute__((ext_vector_type(2))) _Float16;
using f32x2  = __attribute__((ext_vector_type(2))) float;

__device__ __forceinline__ float fast_exp2(float x) {
#if __has_builtin(__builtin_amdgcn_exp2f)
  return __builtin_amdgcn_exp2f(x);
#else
  return exp2f(x);
#endif
}
__device__ __forceinline__ float fast_rcp(float x) {
#if __has_builtin(__builtin_amdgcn_rcpf)
  return __builtin_amdgcn_rcpf(x);
#else
  return 1.0f / x;
#endif
}
__device__ __forceinline__ half2v pack_f16(float y0, float y1) {
  return __builtin_bit_cast(half2v, __builtin_amdgcn_cvt_pkrtz(y0, y1));
}

template <int CTRL>
__device__ __forceinline__ float dpp_add(float x) {
  int yi = __builtin_amdgcn_update_dpp(0, __builtin_bit_cast(int, x),
                                       CTRL, 0xf, 0xf, true);
  return x + __builtin_bit_cast(float, yi);
}

// full 64-lane sum; result valid in lane 63
__device__ __forceinline__ float wave_sum_to_lane63(float x) {
  x = dpp_add<0x111>(x);  // row_shr:1
  x = dpp_add<0x112>(x);  // row_shr:2
  x = dpp_add<0x114>(x);  // row_shr:4
  x = dpp_add<0x118>(x);  // row_shr:8
  x = dpp_add<0x142>(x);  // row_bcast15
  x = dpp_add<0x143>(x);  // row_bcast31 -> lane63 = total
  return x;
}

// barrier WITHOUT vmcnt drain: only LDS ops must be visible across it
#define BAR_LDS_ONLY() asm volatile("s_waitcnt lgkmcnt(0)\n\ts_barrier" ::: "memory")

// ---------------- rowmin: one block per row ----------------
__global__ void softrr_rowmin(const float* __restrict__ V, float* __restrict__ rmin) {
  const int row = blockIdx.x;
  const float* p = V + (size_t)row * M_COLS;
  float m = 1e30f;
  for (int j = threadIdx.x; j < M_COLS; j += 256) m = fminf(m, p[j]);
#pragma unroll
  for (int off = 32; off; off >>= 1) m = fminf(m, __shfl_xor(m, off, 64));
  __shared__ float sm[4];
  if ((threadIdx.x & 63) == 0) sm[threadIdx.x >> 6] = m;
  __syncthreads();
  if (threadIdx.x == 0) {
    rmin[row] = fminf(fminf(sm[0], sm[1]), fminf(sm[2], sm[3]));
  }
}

// ---------------- prep: a = (V - rowmin + 1) * log2e, fp16 ----------------
__global__ void softrr_prep(const float* __restrict__ V, const float* __restrict__ rmin,
                            __half* __restrict__ A) {
  const int idx8 = blockIdx.x * 256 + threadIdx.x;   // 1M half8 groups
  const int row = idx8 >> 10;                        // 1024 half8 per row
  const float mn = rmin[row];
  const float4* v4 = (const float4*)V;
  float4 va = v4[2 * idx8];
  float4 vb = v4[2 * idx8 + 1];
  half8 o;
  o[0] = (_Float16)((va.x - mn + 1.0f) * LOG2E);
  o[1] = (_Float16)((va.y - mn + 1.0f) * LOG2E);
  o[2] = (_Float16)((va.z - mn + 1.0f) * LOG2E);
  o[3] = (_Float16)((va.w - mn + 1.0f) * LOG2E);
  o[4] = (_Float16)((vb.x - mn + 1.0f) * LOG2E);
  o[5] = (_Float16)((vb.y - mn + 1.0f) * LOG2E);
  o[6] = (_Float16)((vb.z - mn + 1.0f) * LOG2E);
  o[7] = (_Float16)((vb.w - mn + 1.0f) * LOG2E);
  ((half8*)A)[idx8] = o;
}

// ---------------- main scan: 512 thr, 16 cols/thread, shadow-store ----------------
__global__ void __launch_bounds__(512) softrr_scan_e(const __half* __restrict__ Ah,
                                                     __half* __restrict__ Eh,
                                                     float* __restrict__ SinvW) {
  const int t = threadIdx.x;          // owns cols 16t..16t+15
  const int wave = t >> 6;            // 0..7
  const int lane = t & 63;
  __shared__ float sP[2][8];

  const half8* __restrict__ A8 = (const half8*)Ah;
  half8* __restrict__ E8 = (half8*)Eh;

  f32x2 c[8];
#pragma unroll
  for (int k = 0; k < 8; ++k) c[k] = (f32x2){1.0f, 1.0f};

  // A prefetch ring, 2 rows deep (fp16: 2 x dwordx4 per step)
  half8 a0 = A8[2 * t];
  half8 a1 = A8[2 * t + 1];
  half8 b0 = A8[1024 + 2 * t];
  half8 b1 = A8[1024 + 2 * t + 1];

  for (int s = 0; s < STEPS; ++s) {
    const int ld  = (s + 2) & (N_ROWS - 1);
    const int par = s & 1;

    half8 n0 = A8[ld * 1024 + 2 * t];
    half8 n1 = A8[ld * 1024 + 2 * t + 1];

    // z = a*c (v_fma_mix: f16 src widened in-instruction), e = exp2(z)
    f32x2 e[8];
#pragma unroll
    for (int k = 0; k < 4; ++k) {
      e[k][0]     = fast_exp2((float)a0[2 * k]     * c[k][0]);
      e[k][1]     = fast_exp2((float)a0[2 * k + 1] * c[k][1]);
      e[4 + k][0] = fast_exp2((float)a1[2 * k]     * c[4 + k][0]);
      e[4 + k][1] = fast_exp2((float)a1[2 * k + 1] * c[4 + k][1]);
    }

    // ce = c*e (pk_mul) — S-independent, issued pre-barrier
    f32x2 ce[8];
#pragma unroll
    for (int k = 0; k < 8; ++k) ce[k] = c[k] * e[k];

    // pack + store unnormalized e (pre-barrier, fully in the reduce shadow)
    half8 o0, o1;
#pragma unroll
    for (int k = 0; k < 4; ++k) {
      half2v h = pack_f16(e[k][0], e[k][1]);
      o0[2 * k] = h[0]; o0[2 * k + 1] = h[1];
      half2v g = pack_f16(e[4 + k][0], e[4 + k][1]);
      o1[2 * k] = g[0]; o1[2 * k + 1] = g[1];
    }
    E8[(size_t)s * 1024 + 2 * t]     = o0;
    E8[(size_t)s * 1024 + 2 * t + 1] = o1;

    // packed tree sum -> scalar
    f32x2 t0 = (e[0] + e[1]) + (e[2] + e[3]);
    f32x2 t1 = (e[4] + e[5]) + (e[6] + e[7]);
    f32x2 tw = t0 + t1;
    float l = tw[0] + tw[1];

    l = wave_sum_to_lane63(l);
    if (lane == 63) sP[par][wave] = l;
    BAR_LDS_ONLY();

    float x = (lane < 8) ? sP[par][lane] : 0.0f;
    x = dpp_add<0x111>(x);
    x = dpp_add<0x112>(x);
    x = dpp_add<0x114>(x);
    const float S = __builtin_bit_cast(
        float, __builtin_amdgcn_readlane(__builtin_bit_cast(int, x), 7));
    const float Sinv = fast_rcp(S);
    if (t == 0) SinvW[s] = Sinv;

    // only S-dependent work: c -= ce*Sinv  (v_pk_fma_f32)
    const f32x2 Sv = (f32x2){Sinv, Sinv};
#pragma unroll
    for (int k = 0; k < 8; ++k) c[k] = c[k] - ce[k] * Sv;

    a0 = b0; a1 = b1;
    b0 = n0; b1 = n1;
  }
}

// ---------------- epilogue: out = sum_r E[r*1024+i] * Sinv[r*1024+i] ----------------
__global__ void softrr_sum8s(const __half* __restrict__ Eh,
                             const float* __restrict__ SinvW,
                             float* __restrict__ out) {
  const int idx8 = blockIdx.x * 256 + threadIdx.x;   // 1M half8 outputs
  const int i = idx8 >> 10;                          // output row
  const int w = idx8 & 1023;                         // half8 within row
  const half8* E8 = (const half8*)Eh;

  float si[8];
#pragma unroll
  for (int r = 0; r < 8; ++r) si[r] = SinvW[r * 1024 + i];

  float acc[8];
#pragma unroll
  for (int k = 0; k < 8; ++k) acc[k] = 0.0f;
#pragma unroll
  for (int r = 0; r < 8; ++r) {
    half8 v = E8[(size_t)(r * 1024 + i) * 1024 + w];
#pragma unroll
    for (int k = 0; k < 8; ++k) acc[k] = __builtin_fmaf((float)v[k], si[r], acc[k]);
  }
  ((float4*)out)[2 * idx8]     = make_float4(acc[0], acc[1], acc[2], acc[3]);
  ((float4*)out)[2 * idx8 + 1] = make_float4(acc[4], acc[5], acc[6], acc[7]);
}

// ---------------- fallback: f32 direct (tiny ws) ----------------
__global__ void __launch_bounds__(1024) softrr_scan_b(const float* __restrict__ V,
                                                      const float* __restrict__ rmin,
                                                      float* __restrict__ out) {
  const int t = threadIdx.x;
  const int wave = t >> 6;
  const int lane = t & 63;
  __shared__ float partials[2][16];
  __shared__ float smin[N_ROWS];
  smin[t] = rmin[t];
  __syncthreads();
  const float4* __restrict__ V4 = (const float4*)V;
  float4* O4 = (float4*)out;
  float c[8];
#pragma unroll
  for (int k = 0; k < 8; ++k) c[k] = 1.0f;
  float4 va = V4[2 * t], vb = V4[2 * t + 1];
  float4 pa, pb;
  for (int s = 0; s < STEPS; ++s) {
    const int i = s & (N_ROWS - 1);
    const int r = s >> 10;
    const int in_ = (s + 1) & (N_ROWS - 1);
    float4 van = V4[in_ * 2048 + 2 * t];
    float4 vbn = V4[in_ * 2048 + 2 * t + 1];
    const float mn = smin[i];
    const float base = (1.0f - mn) * LOG2E;
    float vv[8] = {va.x, va.y, va.z, va.w, vb.x, vb.y, vb.z, vb.w};
    float e[8];
    float l = 0.0f;
#pragma unroll
    for (int k = 0; k < 8; ++k) {
      float zb = __builtin_fmaf(vv[k], LOG2E, base);
      e[k] = fast_exp2(zb * c[k]);
      l += e[k];
    }
#pragma unroll
    for (int off = 32; off; off >>= 1) l += __shfl_xor(l, off, 64);
    if (lane == 0) partials[s & 1][wave] = l;
    __syncthreads();
    float S = 0.0f;
#pragma unroll
    for (int w = 0; w < 16; ++w) S += partials[s & 1][w];
    const float Sinv = fast_rcp(S);
    float po[8] = {pa.x, pa.y, pa.z, pa.w, pb.x, pb.y, pb.z, pb.w};
    float o[8];
#pragma unroll
    for (int k = 0; k < 8; ++k) {
      float y = e[k] * Sinv;
      c[k] = __builtin_fmaf(-y, c[k], c[k]);
      o[k] = (r > 0) ? (po[k] + y) : y;
    }
    O4[i * 2048 + 2 * t]     = make_float4(o[0], o[1], o[2], o[3]);
    O4[i * 2048 + 2 * t + 1] = make_float4(o[4], o[5], o[6], o[7]);
    va = van; vb = vbn;
    pa = O4[in_ * 2048 + 2 * t];
    pb = O4[in_ * 2048 + 2 * t + 1];
  }
}

extern "C" void kernel_launch(void* const* d_in, const int* in_sizes, int n_in,
                              void* d_out, int out_size, void* d_ws, size_t ws_size,
                              hipStream_t stream) {
  const float* V = (const float*)d_in[0];
  float* out = (float*)d_out;
  float* rmin = (float*)d_ws;

  const size_t E_BYTES = (size_t)STEPS * M_COLS * 2;   // 128 MiB
  const size_t S_BYTES = (size_t)STEPS * 4;            // 32 KiB
  const size_t need = 4096 + E_BYTES + S_BYTES;

  if (ws_size >= need) {
    // A (fp16, 16 MiB) lives in d_out's first half; epilogue overwrites d_out.
    __half* A    = (__half*)out;
    __half* E    = (__half*)((char*)d_ws + 4096);
    float*  Sinv = (float*)((char*)d_ws + 4096 + E_BYTES);
    softrr_rowmin<<<N_ROWS, 256, 0, stream>>>(V, rmin);
    softrr_prep<<<4096, 256, 0, stream>>>(V, rmin, A);
    softrr_scan_e<<<1, 512, 0, stream>>>(A, E, Sinv);
    softrr_sum8s<<<4096, 256, 0, stream>>>(E, Sinv, out);
  } else {
    softrr_rowmin<<<N_ROWS, 256, 0, stream>>>(V, rmin);
    softrr_scan_b<<<1, 1024, 0, stream>>>(V, rmin, out);
  }
}

// Round 7
// 5011.767 us; speedup vs baseline: 1.2789x; 1.0274x over previous
//
#include <hip/hip_runtime.h>
#include <hip/hip_fp16.h>

// SoftRR: n=1024, m=8192, rounds=8, TAU=1.0
//   scan over 8192 rows (V tiled x8):
//     y = softmax((row - min(row) + 1) * c);  c = (1-y)*c
//   pi[i][j] = sum over rounds of y
//
// R7: minimum-wave scan. Evidence R1(16w)=2570cy, R4/R6(8w)~1450cy ->
// per-step cost ~ waves/SIMD * instrs. Now 256 thr = 4 waves = 1 wave/SIMD,
// 32 cols/thread; ILP across 32 independent cols replaces TLP.
//  - zero-mov prefetch: unroll x2, two buffer sets (even/odd row); row s+2
//    loads into the buffer just consumed -> no ring rotation movs.
//  - A and E in a thread-permuted layout (chunk q of thread t at q*2048+8t
//    halves) so all scan loads/stores are 16B/lane coalesced.
//  - cross-wave reduce: lane63s write 4 partials; ONE ds_read_b128
//    broadcast + 3 adds (no cndmask/DPP stage-2/readlane).
//  - stores unnormalized e (fp16) + Sinv[s]; epilogue does pi = sum_r e*Sinv.
//  - addressing: uniform SALU offsets, power-of-2 wrap via AND.

#define N_ROWS 1024
#define M_COLS 8192
#define STEPS  8192
#define LOG2E  1.4426950408889634f

using half8  = __attribute__((ext_vector_type(8))) _Float16;
using half2v = __attribute__((ext_vector_type(2))) _Float16;
using f32x2  = __attribute__((ext_vector_type(2))) float;

__device__ __forceinline__ float fast_exp2(float x) {
#if __has_builtin(__builtin_amdgcn_exp2f)
  return __builtin_amdgcn_exp2f(x);
#else
  return exp2f(x);
#endif
}
__device__ __forceinline__ float fast_rcp(float x) {
#if __has_builtin(__builtin_amdgcn_rcpf)
  return __builtin_amdgcn_rcpf(x);
#else
  return 1.0f / x;
#endif
}
__device__ __forceinline__ half2v pack_f16(float y0, float y1) {
  return __builtin_bit_cast(half2v, __builtin_amdgcn_cvt_pkrtz(y0, y1));
}

template <int CTRL>
__device__ __forceinline__ float dpp_add(float x) {
  int yi = __builtin_amdgcn_update_dpp(0, __builtin_bit_cast(int, x),
                                       CTRL, 0xf, 0xf, true);
  return x + __builtin_bit_cast(float, yi);
}

// full 64-lane sum; result valid in lane 63
__device__ __forceinline__ float wave_sum_to_lane63(float x) {
  x = dpp_add<0x111>(x);  // row_shr:1
  x = dpp_add<0x112>(x);  // row_shr:2
  x = dpp_add<0x114>(x);  // row_shr:4
  x = dpp_add<0x118>(x);  // row_shr:8
  x = dpp_add<0x142>(x);  // row_bcast15
  x = dpp_add<0x143>(x);  // row_bcast31 -> lane63 = total
  return x;
}

// barrier WITHOUT vmcnt drain: only LDS ops must be visible across it
#define BAR_LDS_ONLY() asm volatile("s_waitcnt lgkmcnt(0)\n\ts_barrier" ::: "memory")

// ---------------- rowmin: one block per row ----------------
__global__ void softrr_rowmin(const float* __restrict__ V, float* __restrict__ rmin) {
  const int row = blockIdx.x;
  const float* p = V + (size_t)row * M_COLS;
  float m = 1e30f;
  for (int j = threadIdx.x; j < M_COLS; j += 256) m = fminf(m, p[j]);
#pragma unroll
  for (int off = 32; off; off >>= 1) m = fminf(m, __shfl_xor(m, off, 64));
  __shared__ float sm[4];
  if ((threadIdx.x & 63) == 0) sm[threadIdx.x >> 6] = m;
  __syncthreads();
  if (threadIdx.x == 0) {
    rmin[row] = fminf(fminf(sm[0], sm[1]), fminf(sm[2], sm[3]));
  }
}

// ---------------- prep: a = (V - rowmin + 1)*log2e, fp16, PERMUTED ----------------
// Perm: half8-chunk (q,t) of a row sits at perm index q*256+t and holds
// canonical cols 8*(4t+q)..+7.  (q in [0,4), t in [0,256))
__global__ void softrr_prep_perm(const float* __restrict__ V, const float* __restrict__ rmin,
                                 __half* __restrict__ A) {
  const int gid = blockIdx.x * 256 + threadIdx.x;   // 1M perm half8 chunks
  const int row = gid >> 10;
  const int pc  = gid & 1023;
  const int q   = pc >> 8;
  const int tt  = pc & 255;
  const int cc  = 4 * tt + q;                       // canonical half8 chunk
  const float mn = rmin[row];
  const float4* V4 = (const float4*)V;
  float4 va = V4[row * 2048 + 2 * cc];
  float4 vb = V4[row * 2048 + 2 * cc + 1];
  half8 o;
  o[0] = (_Float16)((va.x - mn + 1.0f) * LOG2E);
  o[1] = (_Float16)((va.y - mn + 1.0f) * LOG2E);
  o[2] = (_Float16)((va.z - mn + 1.0f) * LOG2E);
  o[3] = (_Float16)((va.w - mn + 1.0f) * LOG2E);
  o[4] = (_Float16)((vb.x - mn + 1.0f) * LOG2E);
  o[5] = (_Float16)((vb.y - mn + 1.0f) * LOG2E);
  o[6] = (_Float16)((vb.z - mn + 1.0f) * LOG2E);
  o[7] = (_Float16)((vb.w - mn + 1.0f) * LOG2E);
  ((half8*)A)[gid] = o;
}

// ---------------- main scan: 256 thr (4 waves), 32 cols/thread ----------------
__global__ void __launch_bounds__(256) softrr_scan4(const __half* __restrict__ Ah,
                                                    __half* __restrict__ Eh,
                                                    float* __restrict__ SinvW) {
  const int t = threadIdx.x;        // 0..255
  const int wave = t >> 6;          // 0..3
  const int lane = t & 63;
  __shared__ __align__(16) float sP[2][4];

  const half8* __restrict__ A8 = (const half8*)Ah;
  half8* __restrict__ E8 = (half8*)Eh;

  f32x2 c[16];
#pragma unroll
  for (int k = 0; k < 16; ++k) c[k] = (f32x2){1.0f, 1.0f};

  half8 X[4], Y[4];                 // even/odd row buffers
#pragma unroll
  for (int q = 0; q < 4; ++q) X[q] = A8[q * 256 + t];
#pragma unroll
  for (int q = 0; q < 4; ++q) Y[q] = A8[1024 + q * 256 + t];

  unsigned aoffE = 2 * 1024, aoffO = 3 * 1024;   // perm half8 index of prefetch row
  unsigned eoffE = 0,        eoffO = 1024;       // perm half8 index of E row

  auto half_step = [&](half8 (&B)[4], unsigned aoff, unsigned eoff, int par, int s) {
    // e = exp2(a*c)  (B consumed here)
    f32x2 e[16];
#pragma unroll
    for (int q = 0; q < 4; ++q) {
#pragma unroll
      for (int j = 0; j < 4; ++j) {
        const int k = q * 4 + j;
        e[k][0] = fast_exp2((float)B[q][2 * j]     * c[k][0]);
        e[k][1] = fast_exp2((float)B[q][2 * j + 1] * c[k][1]);
      }
    }
    // prefetch row s+2 into the just-freed buffer (no movs)
#pragma unroll
    for (int q = 0; q < 4; ++q) B[q] = A8[aoff + q * 256 + t];

    // pack + store unnormalized e (pre-barrier)
#pragma unroll
    for (int q = 0; q < 4; ++q) {
      half8 o;
#pragma unroll
      for (int j = 0; j < 4; ++j) {
        half2v h = pack_f16(e[q * 4 + j][0], e[q * 4 + j][1]);
        o[2 * j] = h[0]; o[2 * j + 1] = h[1];
      }
      E8[eoff + q * 256 + t] = o;
    }

    // packed tree sum -> scalar
    f32x2 u0 = (e[0] + e[1]) + (e[2] + e[3]);
    f32x2 u1 = (e[4] + e[5]) + (e[6] + e[7]);
    f32x2 u2 = (e[8] + e[9]) + (e[10] + e[11]);
    f32x2 u3 = (e[12] + e[13]) + (e[14] + e[15]);
    f32x2 tw = (u0 + u1) + (u2 + u3);
    float l = tw[0] + tw[1];

    l = wave_sum_to_lane63(l);
    if (lane == 63) sP[par][wave] = l;
    BAR_LDS_ONLY();

    // all threads: one ds_read_b128 broadcast of the 4 partials
    float4 p4 = *(const float4*)(&sP[par][0]);
    const float S = (p4.x + p4.y) + (p4.z + p4.w);
    const float Sinv = fast_rcp(S);
    if (t == 0) SinvW[s] = Sinv;

    // ce overwrites e (register reuse), then c -= ce*Sinv
    const f32x2 Sv = (f32x2){Sinv, Sinv};
#pragma unroll
    for (int k = 0; k < 16; ++k) {
      e[k] = c[k] * e[k];
      c[k] = c[k] - e[k] * Sv;
    }
  };

  for (int s = 0; s < STEPS; s += 2) {
    half_step(X, aoffE, eoffE, 0, s);
    aoffE = (aoffE + 2048) & (1024 * 1024 - 1);
    eoffE += 2048;
    half_step(Y, aoffO, eoffO, 1, s + 1);
    aoffO = (aoffO + 2048) & (1024 * 1024 - 1);
    eoffO += 2048;
  }
}

// ---------------- epilogue: out = sum_r E_perm[r*1024+i] * Sinv, de-permute ----------------
__global__ void softrr_sum8p(const __half* __restrict__ Eh,
                             const float* __restrict__ SinvW,
                             float* __restrict__ out) {
  const int gid = blockIdx.x * 256 + threadIdx.x;   // 1M perm half8 chunks
  const int i  = gid >> 10;                         // output row
  const int pc = gid & 1023;
  const int q  = pc >> 8;
  const int tt = pc & 255;
  const int cc = 4 * tt + q;                        // canonical half8 chunk
  const half8* E8 = (const half8*)Eh;

  float si[8];
#pragma unroll
  for (int r = 0; r < 8; ++r) si[r] = SinvW[r * 1024 + i];

  float acc[8];
#pragma unroll
  for (int k = 0; k < 8; ++k) acc[k] = 0.0f;
#pragma unroll
  for (int r = 0; r < 8; ++r) {
    half8 v = E8[(size_t)(r * 1024 + i) * 1024 + pc];
#pragma unroll
    for (int k = 0; k < 8; ++k) acc[k] = __builtin_fmaf((float)v[k], si[r], acc[k]);
  }
  ((float4*)out)[(size_t)i * 2048 + 2 * cc]     = make_float4(acc[0], acc[1], acc[2], acc[3]);
  ((float4*)out)[(size_t)i * 2048 + 2 * cc + 1] = make_float4(acc[4], acc[5], acc[6], acc[7]);
}

// ---------------- fallback: f32 direct (tiny ws) ----------------
__global__ void __launch_bounds__(1024) softrr_scan_b(const float* __restrict__ V,
                                                      const float* __restrict__ rmin,
                                                      float* __restrict__ out) {
  const int t = threadIdx.x;
  const int wave = t >> 6;
  const int lane = t & 63;
  __shared__ float partials[2][16];
  __shared__ float smin[N_ROWS];
  smin[t] = rmin[t];
  __syncthreads();
  const float4* __restrict__ V4 = (const float4*)V;
  float4* O4 = (float4*)out;
  float c[8];
#pragma unroll
  for (int k = 0; k < 8; ++k) c[k] = 1.0f;
  float4 va = V4[2 * t], vb = V4[2 * t + 1];
  float4 pa, pb;
  for (int s = 0; s < STEPS; ++s) {
    const int i = s & (N_ROWS - 1);
    const int r = s >> 10;
    const int in_ = (s + 1) & (N_ROWS - 1);
    float4 van = V4[in_ * 2048 + 2 * t];
    float4 vbn = V4[in_ * 2048 + 2 * t + 1];
    const float mn = smin[i];
    const float base = (1.0f - mn) * LOG2E;
    float vv[8] = {va.x, va.y, va.z, va.w, vb.x, vb.y, vb.z, vb.w};
    float e[8];
    float l = 0.0f;
#pragma unroll
    for (int k = 0; k < 8; ++k) {
      float zb = __builtin_fmaf(vv[k], LOG2E, base);
      e[k] = fast_exp2(zb * c[k]);
      l += e[k];
    }
#pragma unroll
    for (int off = 32; off; off >>= 1) l += __shfl_xor(l, off, 64);
    if (lane == 0) partials[s & 1][wave] = l;
    __syncthreads();
    float S = 0.0f;
#pragma unroll
    for (int w = 0; w < 16; ++w) S += partials[s & 1][w];
    const float Sinv = fast_rcp(S);
    float po[8] = {pa.x, pa.y, pa.z, pa.w, pb.x, pb.y, pb.z, pb.w};
    float o[8];
#pragma unroll
    for (int k = 0; k < 8; ++k) {
      float y = e[k] * Sinv;
      c[k] = __builtin_fmaf(-y, c[k], c[k]);
      o[k] = (r > 0) ? (po[k] + y) : y;
    }
    O4[i * 2048 + 2 * t]     = make_float4(o[0], o[1], o[2], o[3]);
    O4[i * 2048 + 2 * t + 1] = make_float4(o[4], o[5], o[6], o[7]);
    va = van; vb = vbn;
    pa = O4[in_ * 2048 + 2 * t];
    pb = O4[in_ * 2048 + 2 * t + 1];
  }
}

extern "C" void kernel_launch(void* const* d_in, const int* in_sizes, int n_in,
                              void* d_out, int out_size, void* d_ws, size_t ws_size,
                              hipStream_t stream) {
  const float* V = (const float*)d_in[0];
  float* out = (float*)d_out;
  float* rmin = (float*)d_ws;

  const size_t E_BYTES = (size_t)STEPS * M_COLS * 2;   // 128 MiB
  const size_t S_BYTES = (size_t)STEPS * 4;            // 32 KiB
  const size_t need = 4096 + E_BYTES + S_BYTES;

  if (ws_size >= need) {
    // A (fp16 perm, 16 MiB) lives in d_out's first half; epilogue overwrites d_out.
    __half* A    = (__half*)out;
    __half* E    = (__half*)((char*)d_ws + 4096);
    float*  Sinv = (float*)((char*)d_ws + 4096 + E_BYTES);
    softrr_rowmin<<<N_ROWS, 256, 0, stream>>>(V, rmin);
    softrr_prep_perm<<<4096, 256, 0, stream>>>(V, rmin, A);
    softrr_scan4<<<1, 256, 0, stream>>>(A, E, Sinv);
    softrr_sum8p<<<4096, 256, 0, stream>>>(E, Sinv, out);
  } else {
    softrr_rowmin<<<N_ROWS, 256, 0, stream>>>(V, rmin);
    softrr_scan_b<<<1, 1024, 0, stream>>>(V, rmin, out);
  }
}